// Round 11
// baseline (7856.615 us; speedup 1.0000x reference)
//
#include <hip/hip_runtime.h>
#include <hip/hip_fp16.h>

#define BB 64
#define TT 2048
#define DD 256
#define HH 256
#define CHUNK 256
#define NCHUNK 8
#define PB 8          // batches per serial block
#define RS 264        // A-row stride (f16)
#define NSER 8        // serial blocks
#define GRID 240      // total persistent blocks

typedef _Float16 f16x8 __attribute__((ext_vector_type(8)));
typedef _Float16 f16x4 __attribute__((ext_vector_type(4)));
typedef _Float16 h2t   __attribute__((ext_vector_type(2)));
typedef float    f32x4 __attribute__((ext_vector_type(4)));
union V8 { f16x8 v; h2t p[4]; };

__device__ __forceinline__ float sigm(float v){ return __builtin_amdgcn_rcpf(1.f+__expf(-v)); }
__device__ __forceinline__ float tanh_f(float v){ float e=__expf(2.f*v); return 1.f-2.f*__builtin_amdgcn_rcpf(e+1.f); }

// Pack W [256][1024] f32 (k-major) into f16 layout [k/8][1024][8]
__global__ void pack_w(const float* __restrict__ w, _Float16* __restrict__ o) {
    int idx = blockIdx.x * 256 + threadIdx.x;
    int j = idx & 1023;
    int k = idx >> 10;
    o[(((k >> 3) * 1024) + j) * 8 + (k & 7)] = (_Float16)w[idx];
}

// ---- grid barrier: flat monotonic counter, device scope, fenced ----
__device__ __forceinline__ void gridbar(int* bar, int gen) {
    __syncthreads();
    if (threadIdx.x == 0) {
        __builtin_amdgcn_fence(__ATOMIC_RELEASE, "agent");
        __hip_atomic_fetch_add(bar, 1, __ATOMIC_RELAXED, __HIP_MEMORY_SCOPE_AGENT);
        while (__hip_atomic_load(bar, __ATOMIC_RELAXED, __HIP_MEMORY_SCOPE_AGENT) < GRID * gen)
            __builtin_amdgcn_s_sleep(32);
        __builtin_amdgcn_fence(__ATOMIC_ACQUIRE, "agent");
    }
    __syncthreads();
}

union SMem {
    struct { _Float16 A[2 * 16 * RS]; _Float16 Wl[8 * 1024 * 8]; float bh2l[1024]; } s;
    _Float16 xl[64 * 280];
};

// gx = x @ W_xh + (b_xh + b_hh) for chunk c, grid-strided over gemm blocks.
__device__ void gemm_chunk(const float* __restrict__ x, const f16x8* __restrict__ wxp,
                           const float* __restrict__ b_xh, const float* __restrict__ b_hh,
                           _Float16* __restrict__ gxb, int c, _Float16* xl)
{
    const int tid = threadIdx.x;
    const int t0 = c << 8;
    for (int T = (int)blockIdx.x - NSER; T < 2048; T += (GRID - NSER)) {
        const int rb = T >> 3, nb = T & 7;
        for (int it = 0; it < 8; ++it) {
            int idx = it * 512 + tid, row = idx >> 6, kq = idx & 63;
            int rlin = rb * 64 + row, b = rlin >> 8, tl = rlin & 255;
            float4 v = *(const float4*)&x[((size_t)b * TT + t0 + tl) * DD + kq * 4];
            f16x4 h; h[0]=(_Float16)v.x; h[1]=(_Float16)v.y; h[2]=(_Float16)v.z; h[3]=(_Float16)v.w;
            *(f16x4*)&xl[row * 280 + kq * 4] = h;
        }
        __syncthreads();
        const int ty = tid >> 5, tx = tid & 31;
        const int col0 = nb * 128 + tx * 4;
        float acc[4][4] = {};
#pragma unroll 2
        for (int kk = 0; kk < 32; ++kk) {
            V8 wv[4], xv[4];
#pragma unroll
            for (int c2 = 0; c2 < 4; ++c2) wv[c2].v = wxp[kk * 1024 + col0 + c2];
#pragma unroll
            for (int r = 0; r < 4; ++r) xv[r].v = *(const f16x8*)&xl[(ty + 16 * r) * 280 + kk * 8];
#pragma unroll
            for (int r = 0; r < 4; ++r)
#pragma unroll
                for (int c2 = 0; c2 < 4; ++c2)
#pragma unroll
                    for (int q = 0; q < 4; ++q)
                        acc[r][c2] = __builtin_amdgcn_fdot2(xv[r].p[q], wv[c2].p[q], acc[r][c2], false);
        }
        __syncthreads();
        float bb[4];
#pragma unroll
        for (int c2 = 0; c2 < 4; ++c2) bb[c2] = b_xh[col0 + c2] + b_hh[col0 + c2];
        const int g0 = col0 >> 8, d0 = col0 & 255;
#pragma unroll
        for (int r = 0; r < 4; ++r) {
            int rlin = rb * 64 + ty + 16 * r, b = rlin >> 8, tl = rlin & 255;
#pragma unroll
            for (int c2 = 0; c2 < 4; ++c2)
                gxb[((size_t)(b * CHUNK + tl) * 256 + d0 + c2) * 4 + g0] =
                    (_Float16)(acc[r][c2] + bb[c2]);
        }
    }
}

// ================= serial macros =================
#define FOR_GDH(M) M(0,0) M(0,1) M(1,0) M(1,1) M(2,0) M(2,1) M(3,0) M(3,1)

#define DECLW(g,dh) f16x8 wf_##g##_##dh##_0, wf_##g##_##dh##_1, wf_##g##_##dh##_2, \
                          wf_##g##_##dh##_3, wf_##g##_##dh##_4, wf_##g##_##dh##_5;

#define LOADW1(g,dh,kt) { f16x8 t_; \
    _Pragma("unroll") \
    for (int e = 0; e < 8; ++e) \
        t_[e] = (_Float16)W_hh[(size_t)((kt)*32 + l4*8 + e)*1024 + (g)*256 + wbase + (dh)*16 + l15]; \
    wf_##g##_##dh##_##kt = t_; }

#define LOADW(g,dh) LOADW1(g,dh,0) LOADW1(g,dh,1) LOADW1(g,dh,2) \
                    LOADW1(g,dh,3) LOADW1(g,dh,4) LOADW1(g,dh,5)

#define MFMA4(af, w0, w1, w2, w3) \
    ac0_ = __builtin_amdgcn_mfma_f32_16x16x32_f16(af, w0, ac0_, 0,0,0); \
    ac1_ = __builtin_amdgcn_mfma_f32_16x16x32_f16(af, w1, ac1_, 0,0,0); \
    ac2_ = __builtin_amdgcn_mfma_f32_16x16x32_f16(af, w2, ac2_, 0,0,0); \
    ac3_ = __builtin_amdgcn_mfma_f32_16x16x32_f16(af, w3, ac3_, 0,0,0);

// paired A-fragment reads: both issued before the 8 dependent MFMAs
#define KT2(a,b,dh) { \
    f16x8 afa_ = *(const f16x8*)&Ab[(a)*32 + l4*8]; \
    f16x8 afb_ = *(const f16x8*)&Ab[(b)*32 + l4*8]; \
    MFMA4(afa_, wf_0_##dh##_##a, wf_1_##dh##_##a, wf_2_##dh##_##a, wf_3_##dh##_##a) \
    MFMA4(afb_, wf_0_##dh##_##b, wf_1_##dh##_##b, wf_2_##dh##_##b, wf_3_##dh##_##b) }

#define BLD(g,dh,kt) (*(const f16x8*)&Wl[(size_t)((((kt)-6)*4 + l4)*1024 + (g)*256 + wbase + (dh)*16 + l15)*8])

#define KTL2(dh) { \
    f16x8 afa_ = *(const f16x8*)&Ab[6*32 + l4*8]; \
    f16x8 afb_ = *(const f16x8*)&Ab[7*32 + l4*8]; \
    f16x8 w0_ = BLD(0,dh,6), w1_ = BLD(1,dh,6), w2_ = BLD(2,dh,6), w3_ = BLD(3,dh,6); \
    MFMA4(afa_, w0_, w1_, w2_, w3_) \
    w0_ = BLD(0,dh,7); w1_ = BLD(1,dh,7); w2_ = BLD(2,dh,7); w3_ = BLD(3,dh,7); \
    MFMA4(afb_, w0_, w1_, w2_, w3_) }

#define UPD(j,dh) { \
    const int gb_ = blk*PB + 2*l4 + (j); \
    const int d_  = wbase + (dh)*16 + l15; \
    float h0n_ = 0.f, h1n_ = 0.f; \
    if (l0act) { \
        float gi_ = ac0_[2*(j)] + (float)gv##j##_[0]; \
        float gf_ = ac1_[2*(j)] + (float)gv##j##_[1]; \
        float gg_ = ac2_[2*(j)] + (float)gv##j##_[2]; \
        float go_ = ac3_[2*(j)] + (float)gv##j##_[3]; \
        c0s_##dh[j] = c0s_##dh[j]*sigm(gf_) + sigm(gi_)*tanh_f(gg_); \
        h0n_ = sigm(go_)*tanh_f(c0s_##dh[j]); \
    } \
    if (l1act) { \
        float gi_ = ac0_[2*(j)] + ac0_[2*(j)+1] + bhv_.x; \
        float gf_ = ac1_[2*(j)] + ac1_[2*(j)+1] + bhv_.y; \
        float gg_ = ac2_[2*(j)] + ac2_[2*(j)+1] + bhv_.z; \
        float go_ = ac3_[2*(j)] + ac3_[2*(j)+1] + bhv_.w; \
        c1s_##dh[j] = c1s_##dh[j]*sigm(gf_) + sigm(gi_)*tanh_f(gg_); \
        h1n_ = sigm(go_)*tanh_f(c1s_##dh[j]); \
        out[((size_t)gb_*TT + (t0 + p - 1))*HH + d_] = h1n_; \
    } \
    A[(parx*16 + (2*l4+(j))*2 + 0)*RS + d_] = (_Float16)h0n_; \
    A[(parx*16 + (2*l4+(j))*2 + 1)*RS + d_] = (_Float16)h1n_; \
    if (lastc) { \
        if (l0act && p == CHUNK-1) { out[FIN + gb_*256 + d_] = h0n_; out[FIN + 32768 + gb_*256 + d_] = c0s_##dh[j]; } \
        if (p == nph-1) { out[FIN + 16384 + gb_*256 + d_] = h1n_; out[FIN + 49152 + gb_*256 + d_] = c1s_##dh[j]; } \
    } }

#define HALF(dh) { \
    float4 bhv_ = *(const float4*)&bh2l[(wbase + (dh)*16 + l15)*4]; \
    f16x4 gv0_ = gc0_##dh, gv1_ = gc1_##dh; \
    f32x4 ac0_ = {}, ac1_ = {}, ac2_ = {}, ac3_ = {}; \
    KT2(0,1,dh) KT2(2,3,dh) KT2(4,5,dh) \
    KTL2(dh) \
    UPD(0,dh) UPD(1,dh) }

// Persistent fused kernel: blocks 0..7 = serial recurrence, rest = gx GEMM.
__global__ __launch_bounds__(512, 2) void lstm_coop(
    const float* __restrict__ x,
    const _Float16* __restrict__ wxp16,
    const float* __restrict__ b_xh, const float* __restrict__ b_hh,
    const float* __restrict__ W_hh,
    float* __restrict__ out,
    _Float16* __restrict__ gx0, _Float16* __restrict__ gx1,
    int* __restrict__ bar, int overlap)
{
    __shared__ SMem sm;
    const int tid = threadIdx.x;
    const f16x8* wxp = (const f16x8*)wxp16;

    if (blockIdx.x < NSER) {
        // ================= serial path =================
        _Float16* A   = sm.s.A;
        _Float16* Wl  = sm.s.Wl;
        float* bh2l   = sm.s.bh2l;
        const int blk = blockIdx.x;
        const int l   = tid & 63;
        const int l15 = l & 15;
        const int l4  = l >> 4;
        const int wbase = (tid >> 6) * 32;

        // LDS weights: k in [192,256)
        for (int v = tid; v < 8192; v += 512) {
            int cr = v >> 10, col = v & 1023;
            f16x8 t;
#pragma unroll
            for (int e = 0; e < 8; ++e)
                t[e] = (_Float16)W_hh[(size_t)(192 + cr * 8 + e) * 1024 + col];
            *(f16x8*)&Wl[(size_t)v * 8] = t;
        }
        // 2*b_hh table: bh2l[dim*4+g]
        for (int i = tid; i < 1024; i += 512)
            bh2l[i] = 2.f * b_hh[(i & 3) * 256 + (i >> 2)];

        // register weights: k in [0,192), 48 named f16x8
        FOR_GDH(DECLW)
        FOR_GDH(LOADW)

        float c0s_0[2]={0.f,0.f}, c0s_1[2]={0.f,0.f};
        float c1s_0[2]={0.f,0.f}, c1s_1[2]={0.f,0.f};
        for (int i = tid; i < 16 * RS; i += 512) A[i] = (_Float16)0;

        int gen = 0;
        gridbar(bar, ++gen);                 // wait for chunk-0 gx

        const size_t FIN = (size_t)BB * TT * HH;
        const int dbase = wbase + l15;

        for (int c = 0; c < NCHUNK; ++c) {
            const _Float16* gxc = (c & 1) ? gx1 : gx0;
            const int t0 = c << 8;
            const int nph = (c == NCHUNK - 1) ? CHUNK + 1 : CHUNK;
            const bool lastc = (c == NCHUNK - 1);

            // chunk prologue: prefetch phase-0 gx
            const _Float16* q0 = gxc + ((size_t)((blk*PB + 2*l4 + 0) * CHUNK) * 256 + dbase) * 4;
            const _Float16* q1 = gxc + ((size_t)((blk*PB + 2*l4 + 1) * CHUNK) * 256 + dbase) * 4;
            f16x4 gn0_0 = *(const f16x4*)q0, gn0_1 = *(const f16x4*)(q0 + 64);
            f16x4 gn1_0 = *(const f16x4*)q1, gn1_1 = *(const f16x4*)(q1 + 64);

            for (int p = 0; p < nph; ++p) {
                const int par = p & 1, parx = par ^ 1;
                const bool l0act = (p < CHUNK);
                const bool l1act = (c > 0) || (p > 0);
                const _Float16* Ab = A + (par * 16 + l15) * RS;

                // rotate prefetch -> current; issue next phase's loads NOW
                f16x4 gc0_0 = gn0_0, gc0_1 = gn0_1, gc1_0 = gn1_0, gc1_1 = gn1_1;
                if (p + 1 < CHUNK) {
                    q0 += 1024; q1 += 1024;
                    gn0_0 = *(const f16x4*)q0;  gn0_1 = *(const f16x4*)(q0 + 64);
                    gn1_0 = *(const f16x4*)q1;  gn1_1 = *(const f16x4*)(q1 + 64);
                } else {
                    gn0_0 = (f16x4){}; gn0_1 = (f16x4){}; gn1_0 = (f16x4){}; gn1_1 = (f16x4){};
                }
                asm volatile("" : "+v"(gn0_0), "+v"(gn0_1), "+v"(gn1_0), "+v"(gn1_1));

                HALF(0)
                HALF(1)

                if (p + 1 < nph) __syncthreads();
            }
            if (c < NCHUNK - 1) {
                gridbar(bar, ++gen);
                if (!overlap) gridbar(bar, ++gen);
            }
        }
    } else {
        // ================= gemm path =================
        gemm_chunk(x, wxp, b_xh, b_hh, gx0, 0, sm.xl);
        int gen = 0;
        gridbar(bar, ++gen);
        for (int c = 0; c < NCHUNK - 1; ++c) {
            if (overlap) {
                gemm_chunk(x, wxp, b_xh, b_hh, ((c + 1) & 1) ? gx1 : gx0, c + 1, sm.xl);
                gridbar(bar, ++gen);
            } else {
                gridbar(bar, ++gen);
                gemm_chunk(x, wxp, b_xh, b_hh, gx0, c + 1, sm.xl);
                gridbar(bar, ++gen);
            }
        }
    }
}

extern "C" void kernel_launch(void* const* d_in, const int* in_sizes, int n_in,
                              void* d_out, int out_size, void* d_ws, size_t ws_size,
                              hipStream_t stream) {
    const float* x    = (const float*)d_in[0];
    const float* W_xh = (const float*)d_in[1];
    const float* b_xh = (const float*)d_in[2];
    const float* W_hh = (const float*)d_in[3];
    const float* b_hh = (const float*)d_in[4];
    float* out = (float*)d_out;

    char* ws = (char*)d_ws;
    _Float16* wxp = (_Float16*)ws;                          // 512 KB packed W_xh
    int* bar      = (int*)(ws + (512 << 10));               // barrier counter
    char* gxbase  = ws + (512 << 10) + 256;
    const size_t gxb = (size_t)64 * 256 * 1024 * 2;         // 33.55 MB per gx buffer
    _Float16* gx0 = (_Float16*)gxbase;
    int overlap = (ws_size >= (size_t)(512 << 10) + 256 + 2 * gxb) ? 1 : 0;
    _Float16* gx1 = overlap ? (_Float16*)(gxbase + gxb) : gx0;

    pack_w<<<1024, 256, 0, stream>>>(W_xh, wxp);
    hipMemsetAsync(bar, 0, 4, stream);
    lstm_coop<<<GRID, 512, 0, stream>>>(x, wxp, b_xh, b_hh, W_hh, out, gx0, gx1, bar, overlap);
}

// Round 12
// 6889.302 us; speedup vs baseline: 1.1404x; 1.1404x over previous
//
#include <hip/hip_runtime.h>
#include <hip/hip_fp16.h>

#define BB 64
#define TT 2048
#define DD 256
#define HH 256
#define CHUNK 256
#define NCHUNK 8
#define PB 8          // batches per serial block
#define RS 264        // A-row stride (f16)
#define NSER 8        // serial blocks
#define GRID 240      // total persistent blocks

typedef _Float16 f16x8 __attribute__((ext_vector_type(8)));
typedef _Float16 f16x4 __attribute__((ext_vector_type(4)));
typedef _Float16 h2t   __attribute__((ext_vector_type(2)));
typedef float    f32x4 __attribute__((ext_vector_type(4)));
union V8 { f16x8 v; h2t p[4]; };

__device__ __forceinline__ float sigm(float v){ return __builtin_amdgcn_rcpf(1.f+__expf(-v)); }
__device__ __forceinline__ float tanh_f(float v){ float e=__expf(2.f*v); return 1.f-2.f*__builtin_amdgcn_rcpf(e+1.f); }

// Pack W [256][1024] f32 (k-major) into f16 layout [k/8][1024][8]
__global__ void pack_w(const float* __restrict__ w, _Float16* __restrict__ o) {
    int idx = blockIdx.x * 256 + threadIdx.x;
    int j = idx & 1023;
    int k = idx >> 10;
    o[(((k >> 3) * 1024) + j) * 8 + (k & 7)] = (_Float16)w[idx];
}

// ---- grid barrier: flat monotonic counter, device scope, fenced ----
__device__ __forceinline__ void gridbar(int* bar, int gen) {
    __syncthreads();
    if (threadIdx.x == 0) {
        __builtin_amdgcn_fence(__ATOMIC_RELEASE, "agent");
        __hip_atomic_fetch_add(bar, 1, __ATOMIC_RELAXED, __HIP_MEMORY_SCOPE_AGENT);
        while (__hip_atomic_load(bar, __ATOMIC_RELAXED, __HIP_MEMORY_SCOPE_AGENT) < GRID * gen)
            __builtin_amdgcn_s_sleep(8);
        __builtin_amdgcn_fence(__ATOMIC_ACQUIRE, "agent");
    }
    __syncthreads();
}

union SMem {
    struct { _Float16 A[2 * 16 * RS]; _Float16 Wl[8 * 1024 * 8]; } s;  // 147,968 B
    _Float16 xl[64 * 280];
};

// gx = x @ W_xh + (b_xh + b_hh) for chunk c, grid-strided over gemm blocks.
__device__ void gemm_chunk(const float* __restrict__ x, const f16x8* __restrict__ wxp,
                           const float* __restrict__ b_xh, const float* __restrict__ b_hh,
                           _Float16* __restrict__ gxb, int c, _Float16* xl)
{
    const int tid = threadIdx.x;
    const int t0 = c << 8;
    for (int T = (int)blockIdx.x - NSER; T < 2048; T += (GRID - NSER)) {
        const int rb = T >> 3, nb = T & 7;
        for (int it = 0; it < 8; ++it) {
            int idx = it * 512 + tid, row = idx >> 6, kq = idx & 63;
            int rlin = rb * 64 + row, b = rlin >> 8, tl = rlin & 255;
            float4 v = *(const float4*)&x[((size_t)b * TT + t0 + tl) * DD + kq * 4];
            f16x4 h; h[0]=(_Float16)v.x; h[1]=(_Float16)v.y; h[2]=(_Float16)v.z; h[3]=(_Float16)v.w;
            *(f16x4*)&xl[row * 280 + kq * 4] = h;
        }
        __syncthreads();
        const int ty = tid >> 5, tx = tid & 31;
        const int col0 = nb * 128 + tx * 4;
        float acc[4][4] = {};
#pragma unroll 2
        for (int kk = 0; kk < 32; ++kk) {
            V8 wv[4], xv[4];
#pragma unroll
            for (int c2 = 0; c2 < 4; ++c2) wv[c2].v = wxp[kk * 1024 + col0 + c2];
#pragma unroll
            for (int r = 0; r < 4; ++r) xv[r].v = *(const f16x8*)&xl[(ty + 16 * r) * 280 + kk * 8];
#pragma unroll
            for (int r = 0; r < 4; ++r)
#pragma unroll
                for (int c2 = 0; c2 < 4; ++c2)
#pragma unroll
                    for (int q = 0; q < 4; ++q)
                        acc[r][c2] = __builtin_amdgcn_fdot2(xv[r].p[q], wv[c2].p[q], acc[r][c2], false);
        }
        __syncthreads();
        float bb[4];
#pragma unroll
        for (int c2 = 0; c2 < 4; ++c2) bb[c2] = b_xh[col0 + c2] + b_hh[col0 + c2];
        const int g0 = col0 >> 8, d0 = col0 & 255;
#pragma unroll
        for (int r = 0; r < 4; ++r) {
            int rlin = rb * 64 + ty + 16 * r, b = rlin >> 8, tl = rlin & 255;
#pragma unroll
            for (int c2 = 0; c2 < 4; ++c2)
                gxb[((size_t)(b * CHUNK + tl) * 256 + d0 + c2) * 4 + g0] =
                    (_Float16)(acc[r][c2] + bb[c2]);
        }
    }
}

// ================= serial macros (r10 verbatim) =================
#define FOR_GDH(M) M(0,0) M(0,1) M(1,0) M(1,1) M(2,0) M(2,1) M(3,0) M(3,1)

#define DECLW(g,dh) f16x8 wf_##g##_##dh##_0, wf_##g##_##dh##_1, wf_##g##_##dh##_2, \
                          wf_##g##_##dh##_3, wf_##g##_##dh##_4, wf_##g##_##dh##_5;

#define LOADW1(g,dh,kt) { f16x8 t_; \
    _Pragma("unroll") \
    for (int e = 0; e < 8; ++e) \
        t_[e] = (_Float16)W_hh[(size_t)((kt)*32 + l4*8 + e)*1024 + (g)*256 + wbase + (dh)*16 + l15]; \
    wf_##g##_##dh##_##kt = t_; }

#define LOADW(g,dh) LOADW1(g,dh,0) LOADW1(g,dh,1) LOADW1(g,dh,2) \
                    LOADW1(g,dh,3) LOADW1(g,dh,4) LOADW1(g,dh,5)

#define KTR(kt,dh) { f16x8 af_ = *(const f16x8*)&Ab[(kt)*32 + l4*8]; \
    ac0_ = __builtin_amdgcn_mfma_f32_16x16x32_f16(af_, wf_0_##dh##_##kt, ac0_, 0,0,0); \
    ac1_ = __builtin_amdgcn_mfma_f32_16x16x32_f16(af_, wf_1_##dh##_##kt, ac1_, 0,0,0); \
    ac2_ = __builtin_amdgcn_mfma_f32_16x16x32_f16(af_, wf_2_##dh##_##kt, ac2_, 0,0,0); \
    ac3_ = __builtin_amdgcn_mfma_f32_16x16x32_f16(af_, wf_3_##dh##_##kt, ac3_, 0,0,0); }

#define BLD(g,dh,kt) (*(const f16x8*)&Wl[(size_t)((((kt)-6)*4 + l4)*1024 + (g)*256 + wbase + (dh)*16 + l15)*8])

#define KTL(kt,dh) { f16x8 af_ = *(const f16x8*)&Ab[(kt)*32 + l4*8]; \
    ac0_ = __builtin_amdgcn_mfma_f32_16x16x32_f16(af_, BLD(0,dh,kt), ac0_, 0,0,0); \
    ac1_ = __builtin_amdgcn_mfma_f32_16x16x32_f16(af_, BLD(1,dh,kt), ac1_, 0,0,0); \
    ac2_ = __builtin_amdgcn_mfma_f32_16x16x32_f16(af_, BLD(2,dh,kt), ac2_, 0,0,0); \
    ac3_ = __builtin_amdgcn_mfma_f32_16x16x32_f16(af_, BLD(3,dh,kt), ac3_, 0,0,0); }

#define UPD(j,dh) { \
    const int gb_ = blk*PB + 2*l4 + (j); \
    const int d_  = wbase + (dh)*16 + l15; \
    float h0n_ = 0.f, h1n_ = 0.f; \
    if (l0act) { \
        float gi_ = ac0_[2*(j)] + (float)gv##j##_[0]; \
        float gf_ = ac1_[2*(j)] + (float)gv##j##_[1]; \
        float gg_ = ac2_[2*(j)] + (float)gv##j##_[2]; \
        float go_ = ac3_[2*(j)] + (float)gv##j##_[3]; \
        c0s_##dh[j] = c0s_##dh[j]*sigm(gf_) + sigm(gi_)*tanh_f(gg_); \
        h0n_ = sigm(go_)*tanh_f(c0s_##dh[j]); \
    } \
    if (l1act) { \
        float gi_ = ac0_[2*(j)] + ac0_[2*(j)+1] + bh2_##dh##_0; \
        float gf_ = ac1_[2*(j)] + ac1_[2*(j)+1] + bh2_##dh##_1; \
        float gg_ = ac2_[2*(j)] + ac2_[2*(j)+1] + bh2_##dh##_2; \
        float go_ = ac3_[2*(j)] + ac3_[2*(j)+1] + bh2_##dh##_3; \
        c1s_##dh[j] = c1s_##dh[j]*sigm(gf_) + sigm(gi_)*tanh_f(gg_); \
        h1n_ = sigm(go_)*tanh_f(c1s_##dh[j]); \
        out[((size_t)gb_*TT + (t0 + p - 1))*HH + d_] = h1n_; \
    } \
    A[(parx*16 + (2*l4+(j))*2 + 0)*RS + d_] = (_Float16)h0n_; \
    A[(parx*16 + (2*l4+(j))*2 + 1)*RS + d_] = (_Float16)h1n_; \
    if (lastc) { \
        if (l0act && p == CHUNK-1) { out[FIN + gb_*256 + d_] = h0n_; out[FIN + 32768 + gb_*256 + d_] = c0s_##dh[j]; } \
        if (p == nph-1) { out[FIN + 16384 + gb_*256 + d_] = h1n_; out[FIN + 49152 + gb_*256 + d_] = c1s_##dh[j]; } \
    } }

#define HALF(dh) { \
    f16x4 gv0_ = {}, gv1_ = {}; \
    if (l0act) { \
        gv0_ = *(const f16x4*)&gxc[((size_t)((blk*PB + 2*l4 + 0)*CHUNK + p)*256 + wbase + (dh)*16 + l15)*4]; \
        gv1_ = *(const f16x4*)&gxc[((size_t)((blk*PB + 2*l4 + 1)*CHUNK + p)*256 + wbase + (dh)*16 + l15)*4]; \
    } \
    f32x4 ac0_ = {}, ac1_ = {}, ac2_ = {}, ac3_ = {}; \
    KTR(0,dh) KTR(1,dh) KTR(2,dh) KTR(3,dh) KTR(4,dh) KTR(5,dh) \
    KTL(6,dh) KTL(7,dh) \
    UPD(0,dh) UPD(1,dh) }

// Persistent fused kernel: blocks 0..7 = serial recurrence, rest = gx GEMM.
__global__ __launch_bounds__(512, 2) void lstm_coop(
    const float* __restrict__ x,
    const _Float16* __restrict__ wxp16,
    const float* __restrict__ b_xh, const float* __restrict__ b_hh,
    const float* __restrict__ W_hh,
    float* __restrict__ out,
    _Float16* __restrict__ gx0, _Float16* __restrict__ gx1,
    int* __restrict__ bar, int overlap)
{
    __shared__ SMem sm;
    const int tid = threadIdx.x;
    const f16x8* wxp = (const f16x8*)wxp16;

    if (blockIdx.x < NSER) {
        // ================= serial path =================
        _Float16* A  = sm.s.A;
        _Float16* Wl = sm.s.Wl;
        const int blk = blockIdx.x;
        const int l   = tid & 63;
        const int l15 = l & 15;
        const int l4  = l >> 4;
        const int wbase = (tid >> 6) * 32;

        // LDS weights: k in [192,256)
        for (int v = tid; v < 8192; v += 512) {
            int cr = v >> 10, col = v & 1023;
            f16x8 t;
#pragma unroll
            for (int e = 0; e < 8; ++e)
                t[e] = (_Float16)W_hh[(size_t)(192 + cr * 8 + e) * 1024 + col];
            *(f16x8*)&Wl[(size_t)v * 8] = t;
        }
        // register weights: k in [0,192), 48 named f16x8
        FOR_GDH(DECLW)
        FOR_GDH(LOADW)

        float bh2_0_0 = 2.f*b_hh[0*256 + wbase + l15],      bh2_0_1 = 2.f*b_hh[1*256 + wbase + l15];
        float bh2_0_2 = 2.f*b_hh[2*256 + wbase + l15],      bh2_0_3 = 2.f*b_hh[3*256 + wbase + l15];
        float bh2_1_0 = 2.f*b_hh[0*256 + wbase + 16 + l15], bh2_1_1 = 2.f*b_hh[1*256 + wbase + 16 + l15];
        float bh2_1_2 = 2.f*b_hh[2*256 + wbase + 16 + l15], bh2_1_3 = 2.f*b_hh[3*256 + wbase + 16 + l15];

        float c0s_0[2]={0.f,0.f}, c0s_1[2]={0.f,0.f};
        float c1s_0[2]={0.f,0.f}, c1s_1[2]={0.f,0.f};
        for (int i = tid; i < 16 * RS; i += 512) A[i] = (_Float16)0;

        int gen = 0;
        gridbar(bar, ++gen);                 // wait for chunk-0 gx

        const size_t FIN = (size_t)BB * TT * HH;
        for (int c = 0; c < NCHUNK; ++c) {
            const _Float16* gxc = (c & 1) ? gx1 : gx0;
            const int t0 = c << 8;
            const int nph = (c == NCHUNK - 1) ? CHUNK + 1 : CHUNK;
            const bool lastc = (c == NCHUNK - 1);
            for (int p = 0; p < nph; ++p) {
                const int par = p & 1, parx = par ^ 1;
                const bool l0act = (p < CHUNK);
                const bool l1act = (c > 0) || (p > 0);
                const _Float16* Ab = A + (par * 16 + l15) * RS;
                HALF(0)
                HALF(1)
                if (p + 1 < nph) {
                    // raw barrier: only LDS (A) writes must be visible cross-wave.
                    // Skips __syncthreads' vmcnt(0) drain of the out[] store acks
                    // (nothing reads them before kernel end; end-of-pipe flushes).
                    asm volatile("s_waitcnt lgkmcnt(0)" ::: "memory");
                    __builtin_amdgcn_s_barrier();
                }
            }
            if (c < NCHUNK - 1) {
                gridbar(bar, ++gen);
                if (!overlap) gridbar(bar, ++gen);
            }
        }
    } else {
        // ================= gemm path =================
        gemm_chunk(x, wxp, b_xh, b_hh, gx0, 0, sm.xl);
        int gen = 0;
        gridbar(bar, ++gen);
        for (int c = 0; c < NCHUNK - 1; ++c) {
            if (overlap) {
                gemm_chunk(x, wxp, b_xh, b_hh, ((c + 1) & 1) ? gx1 : gx0, c + 1, sm.xl);
                gridbar(bar, ++gen);
            } else {
                gridbar(bar, ++gen);
                gemm_chunk(x, wxp, b_xh, b_hh, gx0, c + 1, sm.xl);
                gridbar(bar, ++gen);
            }
        }
    }
}

extern "C" void kernel_launch(void* const* d_in, const int* in_sizes, int n_in,
                              void* d_out, int out_size, void* d_ws, size_t ws_size,
                              hipStream_t stream) {
    const float* x    = (const float*)d_in[0];
    const float* W_xh = (const float*)d_in[1];
    const float* b_xh = (const float*)d_in[2];
    const float* W_hh = (const float*)d_in[3];
    const float* b_hh = (const float*)d_in[4];
    float* out = (float*)d_out;

    char* ws = (char*)d_ws;
    _Float16* wxp = (_Float16*)ws;                          // 512 KB packed W_xh
    int* bar      = (int*)(ws + (512 << 10));               // barrier counter
    char* gxbase  = ws + (512 << 10) + 256;
    const size_t gxb = (size_t)64 * 256 * 1024 * 2;         // 33.55 MB per gx buffer
    _Float16* gx0 = (_Float16*)gxbase;
    int overlap = (ws_size >= (size_t)(512 << 10) + 256 + 2 * gxb) ? 1 : 0;
    _Float16* gx1 = overlap ? (_Float16*)(gxbase + gxb) : gx0;

    pack_w<<<1024, 256, 0, stream>>>(W_xh, wxp);
    hipMemsetAsync(bar, 0, 4, stream);
    lstm_coop<<<GRID, 512, 0, stream>>>(x, wxp, b_xh, b_hh, W_hh, out, gx0, gx1, bar, overlap);
}

// Round 13
// 6820.593 us; speedup vs baseline: 1.1519x; 1.0101x over previous
//
#include <hip/hip_runtime.h>
#include <hip/hip_fp16.h>

#define BB 64
#define TT 2048
#define DD 256
#define HH 256
#define CHUNK 256
#define NCHUNK 8
#define PB 8          // batches per serial block
#define RS 264        // A-row stride (f16)
#define NSER 8        // serial blocks
#define GRID 240      // total persistent blocks

typedef _Float16 f16x8 __attribute__((ext_vector_type(8)));
typedef _Float16 f16x4 __attribute__((ext_vector_type(4)));
typedef _Float16 h2t   __attribute__((ext_vector_type(2)));
typedef float    f32x4 __attribute__((ext_vector_type(4)));
union V8 { f16x8 v; h2t p[4]; };

__device__ __forceinline__ float sigm(float v){ return __builtin_amdgcn_rcpf(1.f+__expf(-v)); }
__device__ __forceinline__ float tanh_f(float v){ float e=__expf(2.f*v); return 1.f-2.f*__builtin_amdgcn_rcpf(e+1.f); }

// Pack W [256][1024] f32 (k-major) into f16 layout [k/8][1024][8]
__global__ void pack_w(const float* __restrict__ w, _Float16* __restrict__ o) {
    int idx = blockIdx.x * 256 + threadIdx.x;
    int j = idx & 1023;
    int k = idx >> 10;
    o[(((k >> 3) * 1024) + j) * 8 + (k & 7)] = (_Float16)w[idx];
}

// ---- grid barrier: flat monotonic counter, device scope, fenced ----
__device__ __forceinline__ void gridbar(int* bar, int gen) {
    __syncthreads();
    if (threadIdx.x == 0) {
        __builtin_amdgcn_fence(__ATOMIC_RELEASE, "agent");
        __hip_atomic_fetch_add(bar, 1, __ATOMIC_RELAXED, __HIP_MEMORY_SCOPE_AGENT);
        while (__hip_atomic_load(bar, __ATOMIC_RELAXED, __HIP_MEMORY_SCOPE_AGENT) < GRID * gen)
            __builtin_amdgcn_s_sleep(8);
        __builtin_amdgcn_fence(__ATOMIC_ACQUIRE, "agent");
    }
    __syncthreads();
}

union SMem {
    struct { _Float16 A[2 * 16 * RS]; _Float16 Wl[8 * 1024 * 8]; } s;  // 147,968 B
    _Float16 xl[64 * 280];
};

// gx = x @ W_xh + (b_xh + b_hh) for chunk c, grid-strided over gemm blocks.
// Each thread owns the 4 GATES of one dim -> epilogue is ONE contiguous f16x4
// store per row (32 adjacent lanes = 256B full-line writes, single writer).
__device__ void gemm_chunk(const float* __restrict__ x, const f16x8* __restrict__ wxp,
                           const float* __restrict__ b_xh, const float* __restrict__ b_hh,
                           _Float16* __restrict__ gxb, int c, _Float16* xl)
{
    const int tid = threadIdx.x;
    const int t0 = c << 8;
    const int tx = tid & 31;       // dim within block's 32-dim slice
    const int ty = tid >> 5;       // row group 0..15
    for (int T = (int)blockIdx.x - NSER; T < 2048; T += (GRID - NSER)) {
        const int rb = T >> 3, nb = T & 7;
        const int d = nb * 32 + tx;                 // this thread's dim
        for (int it = 0; it < 8; ++it) {
            int idx = it * 512 + tid, row = idx >> 6, kq = idx & 63;
            int rlin = rb * 64 + row, b = rlin >> 8, tl = rlin & 255;
            float4 v = *(const float4*)&x[((size_t)b * TT + t0 + tl) * DD + kq * 4];
            f16x4 h; h[0]=(_Float16)v.x; h[1]=(_Float16)v.y; h[2]=(_Float16)v.z; h[3]=(_Float16)v.w;
            *(f16x4*)&xl[row * 280 + kq * 4] = h;
        }
        __syncthreads();
        float acc[4][4] = {};                       // [row][gate]
#pragma unroll 2
        for (int kk = 0; kk < 32; ++kk) {
            V8 wv[4], xv[4];
#pragma unroll
            for (int g = 0; g < 4; ++g) wv[g].v = wxp[kk * 1024 + g * 256 + d];
#pragma unroll
            for (int r = 0; r < 4; ++r) xv[r].v = *(const f16x8*)&xl[(ty + 16 * r) * 280 + kk * 8];
#pragma unroll
            for (int r = 0; r < 4; ++r)
#pragma unroll
                for (int g = 0; g < 4; ++g)
#pragma unroll
                    for (int q = 0; q < 4; ++q)
                        acc[r][g] = __builtin_amdgcn_fdot2(xv[r].p[q], wv[g].p[q], acc[r][g], false);
        }
        __syncthreads();
        float bb[4];
#pragma unroll
        for (int g = 0; g < 4; ++g) bb[g] = b_xh[g * 256 + d] + b_hh[g * 256 + d];
#pragma unroll
        for (int r = 0; r < 4; ++r) {
            int rlin = rb * 64 + ty + 16 * r, b = rlin >> 8, tl = rlin & 255;
            f16x4 o;
#pragma unroll
            for (int g = 0; g < 4; ++g) o[g] = (_Float16)(acc[r][g] + bb[g]);
            *(f16x4*)&gxb[((size_t)(b * CHUNK + tl) * 256 + d) * 4] = o;
        }
    }
}

// ================= serial macros (r10 verbatim) =================
#define FOR_GDH(M) M(0,0) M(0,1) M(1,0) M(1,1) M(2,0) M(2,1) M(3,0) M(3,1)

#define DECLW(g,dh) f16x8 wf_##g##_##dh##_0, wf_##g##_##dh##_1, wf_##g##_##dh##_2, \
                          wf_##g##_##dh##_3, wf_##g##_##dh##_4, wf_##g##_##dh##_5;

#define LOADW1(g,dh,kt) { f16x8 t_; \
    _Pragma("unroll") \
    for (int e = 0; e < 8; ++e) \
        t_[e] = (_Float16)W_hh[(size_t)((kt)*32 + l4*8 + e)*1024 + (g)*256 + wbase + (dh)*16 + l15]; \
    wf_##g##_##dh##_##kt = t_; }

#define LOADW(g,dh) LOADW1(g,dh,0) LOADW1(g,dh,1) LOADW1(g,dh,2) \
                    LOADW1(g,dh,3) LOADW1(g,dh,4) LOADW1(g,dh,5)

#define KTR(kt,dh) { f16x8 af_ = *(const f16x8*)&Ab[(kt)*32 + l4*8]; \
    ac0_ = __builtin_amdgcn_mfma_f32_16x16x32_f16(af_, wf_0_##dh##_##kt, ac0_, 0,0,0); \
    ac1_ = __builtin_amdgcn_mfma_f32_16x16x32_f16(af_, wf_1_##dh##_##kt, ac1_, 0,0,0); \
    ac2_ = __builtin_amdgcn_mfma_f32_16x16x32_f16(af_, wf_2_##dh##_##kt, ac2_, 0,0,0); \
    ac3_ = __builtin_amdgcn_mfma_f32_16x16x32_f16(af_, wf_3_##dh##_##kt, ac3_, 0,0,0); }

#define BLD(g,dh,kt) (*(const f16x8*)&Wl[(size_t)((((kt)-6)*4 + l4)*1024 + (g)*256 + wbase + (dh)*16 + l15)*8])

#define KTL(kt,dh) { f16x8 af_ = *(const f16x8*)&Ab[(kt)*32 + l4*8]; \
    ac0_ = __builtin_amdgcn_mfma_f32_16x16x32_f16(af_, BLD(0,dh,kt), ac0_, 0,0,0); \
    ac1_ = __builtin_amdgcn_mfma_f32_16x16x32_f16(af_, BLD(1,dh,kt), ac1_, 0,0,0); \
    ac2_ = __builtin_amdgcn_mfma_f32_16x16x32_f16(af_, BLD(2,dh,kt), ac2_, 0,0,0); \
    ac3_ = __builtin_amdgcn_mfma_f32_16x16x32_f16(af_, BLD(3,dh,kt), ac3_, 0,0,0); }

#define UPD(j,dh) { \
    const int gb_ = blk*PB + 2*l4 + (j); \
    const int d_  = wbase + (dh)*16 + l15; \
    float h0n_ = 0.f, h1n_ = 0.f; \
    if (l0act) { \
        float gi_ = ac0_[2*(j)] + (float)gv##j##_[0]; \
        float gf_ = ac1_[2*(j)] + (float)gv##j##_[1]; \
        float gg_ = ac2_[2*(j)] + (float)gv##j##_[2]; \
        float go_ = ac3_[2*(j)] + (float)gv##j##_[3]; \
        c0s_##dh[j] = c0s_##dh[j]*sigm(gf_) + sigm(gi_)*tanh_f(gg_); \
        h0n_ = sigm(go_)*tanh_f(c0s_##dh[j]); \
    } \
    if (l1act) { \
        float gi_ = ac0_[2*(j)] + ac0_[2*(j)+1] + bh2_##dh##_0; \
        float gf_ = ac1_[2*(j)] + ac1_[2*(j)+1] + bh2_##dh##_1; \
        float gg_ = ac2_[2*(j)] + ac2_[2*(j)+1] + bh2_##dh##_2; \
        float go_ = ac3_[2*(j)] + ac3_[2*(j)+1] + bh2_##dh##_3; \
        c1s_##dh[j] = c1s_##dh[j]*sigm(gf_) + sigm(gi_)*tanh_f(gg_); \
        h1n_ = sigm(go_)*tanh_f(c1s_##dh[j]); \
        out[((size_t)gb_*TT + (t0 + p - 1))*HH + d_] = h1n_; \
    } \
    A[(parx*16 + (2*l4+(j))*2 + 0)*RS + d_] = (_Float16)h0n_; \
    A[(parx*16 + (2*l4+(j))*2 + 1)*RS + d_] = (_Float16)h1n_; \
    if (lastc) { \
        if (l0act && p == CHUNK-1) { out[FIN + gb_*256 + d_] = h0n_; out[FIN + 32768 + gb_*256 + d_] = c0s_##dh[j]; } \
        if (p == nph-1) { out[FIN + 16384 + gb_*256 + d_] = h1n_; out[FIN + 49152 + gb_*256 + d_] = c1s_##dh[j]; } \
    } }

#define HALF(dh) { \
    f16x4 gv0_ = {}, gv1_ = {}; \
    if (l0act) { \
        gv0_ = *(const f16x4*)&gxc[((size_t)((blk*PB + 2*l4 + 0)*CHUNK + p)*256 + wbase + (dh)*16 + l15)*4]; \
        gv1_ = *(const f16x4*)&gxc[((size_t)((blk*PB + 2*l4 + 1)*CHUNK + p)*256 + wbase + (dh)*16 + l15)*4]; \
    } \
    f32x4 ac0_ = {}, ac1_ = {}, ac2_ = {}, ac3_ = {}; \
    KTR(0,dh) KTR(1,dh) KTR(2,dh) KTR(3,dh) KTR(4,dh) KTR(5,dh) \
    KTL(6,dh) KTL(7,dh) \
    UPD(0,dh) UPD(1,dh) }

// Persistent fused kernel: blocks 0..7 = serial recurrence, rest = gx GEMM.
__global__ __launch_bounds__(512, 2) void lstm_coop(
    const float* __restrict__ x,
    const _Float16* __restrict__ wxp16,
    const float* __restrict__ b_xh, const float* __restrict__ b_hh,
    const float* __restrict__ W_hh,
    float* __restrict__ out,
    _Float16* __restrict__ gx0, _Float16* __restrict__ gx1,
    int* __restrict__ bar, int overlap)
{
    __shared__ SMem sm;
    const int tid = threadIdx.x;
    const f16x8* wxp = (const f16x8*)wxp16;

    if (blockIdx.x < NSER) {
        // ================= serial path =================
        _Float16* A  = sm.s.A;
        _Float16* Wl = sm.s.Wl;
        const int blk = blockIdx.x;
        const int l   = tid & 63;
        const int l15 = l & 15;
        const int l4  = l >> 4;
        const int wbase = (tid >> 6) * 32;

        // LDS weights: k in [192,256)
        for (int v = tid; v < 8192; v += 512) {
            int cr = v >> 10, col = v & 1023;
            f16x8 t;
#pragma unroll
            for (int e = 0; e < 8; ++e)
                t[e] = (_Float16)W_hh[(size_t)(192 + cr * 8 + e) * 1024 + col];
            *(f16x8*)&Wl[(size_t)v * 8] = t;
        }
        // register weights: k in [0,192), 48 named f16x8
        FOR_GDH(DECLW)
        FOR_GDH(LOADW)

        float bh2_0_0 = 2.f*b_hh[0*256 + wbase + l15],      bh2_0_1 = 2.f*b_hh[1*256 + wbase + l15];
        float bh2_0_2 = 2.f*b_hh[2*256 + wbase + l15],      bh2_0_3 = 2.f*b_hh[3*256 + wbase + l15];
        float bh2_1_0 = 2.f*b_hh[0*256 + wbase + 16 + l15], bh2_1_1 = 2.f*b_hh[1*256 + wbase + 16 + l15];
        float bh2_1_2 = 2.f*b_hh[2*256 + wbase + 16 + l15], bh2_1_3 = 2.f*b_hh[3*256 + wbase + 16 + l15];

        float c0s_0[2]={0.f,0.f}, c0s_1[2]={0.f,0.f};
        float c1s_0[2]={0.f,0.f}, c1s_1[2]={0.f,0.f};
        for (int i = tid; i < 16 * RS; i += 512) A[i] = (_Float16)0;

        int gen = 0;
        gridbar(bar, ++gen);                 // wait for chunk-0 gx

        const size_t FIN = (size_t)BB * TT * HH;
        for (int c = 0; c < NCHUNK; ++c) {
            const _Float16* gxc = (c & 1) ? gx1 : gx0;
            const int t0 = c << 8;
            const int nph = (c == NCHUNK - 1) ? CHUNK + 1 : CHUNK;
            const bool lastc = (c == NCHUNK - 1);
            for (int p = 0; p < nph; ++p) {
                const int par = p & 1, parx = par ^ 1;
                const bool l0act = (p < CHUNK);
                const bool l1act = (c > 0) || (p > 0);
                const _Float16* Ab = A + (par * 16 + l15) * RS;
                HALF(0)
                HALF(1)
                if (p + 1 < nph) {
                    // raw barrier: only LDS (A) writes must be visible cross-wave.
                    asm volatile("s_waitcnt lgkmcnt(0)" ::: "memory");
                    __builtin_amdgcn_s_barrier();
                }
            }
            if (c < NCHUNK - 1) {
                gridbar(bar, ++gen);
                if (!overlap) gridbar(bar, ++gen);
            }
        }
    } else {
        // ================= gemm path =================
        gemm_chunk(x, wxp, b_xh, b_hh, gx0, 0, sm.xl);
        int gen = 0;
        gridbar(bar, ++gen);
        for (int c = 0; c < NCHUNK - 1; ++c) {
            if (overlap) {
                gemm_chunk(x, wxp, b_xh, b_hh, ((c + 1) & 1) ? gx1 : gx0, c + 1, sm.xl);
                gridbar(bar, ++gen);
            } else {
                gridbar(bar, ++gen);
                gemm_chunk(x, wxp, b_xh, b_hh, gx0, c + 1, sm.xl);
                gridbar(bar, ++gen);
            }
        }
    }
}

extern "C" void kernel_launch(void* const* d_in, const int* in_sizes, int n_in,
                              void* d_out, int out_size, void* d_ws, size_t ws_size,
                              hipStream_t stream) {
    const float* x    = (const float*)d_in[0];
    const float* W_xh = (const float*)d_in[1];
    const float* b_xh = (const float*)d_in[2];
    const float* W_hh = (const float*)d_in[3];
    const float* b_hh = (const float*)d_in[4];
    float* out = (float*)d_out;

    char* ws = (char*)d_ws;
    _Float16* wxp = (_Float16*)ws;                          // 512 KB packed W_xh
    int* bar      = (int*)(ws + (512 << 10));               // barrier counter
    char* gxbase  = ws + (512 << 10) + 256;
    const size_t gxb = (size_t)64 * 256 * 1024 * 2;         // 33.55 MB per gx buffer
    _Float16* gx0 = (_Float16*)gxbase;
    int overlap = (ws_size >= (size_t)(512 << 10) + 256 + 2 * gxb) ? 1 : 0;
    _Float16* gx1 = overlap ? (_Float16*)(gxbase + gxb) : gx0;

    pack_w<<<1024, 256, 0, stream>>>(W_xh, wxp);
    hipMemsetAsync(bar, 0, 4, stream);
    lstm_coop<<<GRID, 512, 0, stream>>>(x, wxp, b_xh, b_hh, W_hh, out, gx0, gx1, bar, overlap);
}

// Round 15
// 4671.047 us; speedup vs baseline: 1.6820x; 1.4602x over previous
//
#include <hip/hip_runtime.h>
#include <hip/hip_fp16.h>

#define BB 64
#define TT 2048
#define DD 256
#define HH 256
#define CHUNK 256
#define NCHUNK 8
#define PB 4          // batches per serial block
#define RS 264        // A-row stride (f16)
#define NSER 16       // serial blocks
#define GRID 240      // total persistent blocks

typedef _Float16 f16x8 __attribute__((ext_vector_type(8)));
typedef _Float16 f16x4 __attribute__((ext_vector_type(4)));
typedef _Float16 h2t   __attribute__((ext_vector_type(2)));
typedef float    f32x4 __attribute__((ext_vector_type(4)));
union V8 { f16x8 v; h2t p[4]; };

__device__ __forceinline__ float sigm(float v){ return __builtin_amdgcn_rcpf(1.f+__expf(-v)); }
__device__ __forceinline__ float tanh_f(float v){ float e=__expf(2.f*v); return 1.f-2.f*__builtin_amdgcn_rcpf(e+1.f); }

// Pack W [256][1024] f32 (k-major) into f16 layout [k/8][1024][8]
__global__ void pack_w(const float* __restrict__ w, _Float16* __restrict__ o) {
    int idx = blockIdx.x * 256 + threadIdx.x;
    int j = idx & 1023;
    int k = idx >> 10;
    o[(((k >> 3) * 1024) + j) * 8 + (k & 7)] = (_Float16)w[idx];
}

// ---- grid barrier: flat monotonic counter, device scope, fenced ----
__device__ __forceinline__ void gridbar(int* bar, int gen) {
    __syncthreads();
    if (threadIdx.x == 0) {
        __builtin_amdgcn_fence(__ATOMIC_RELEASE, "agent");
        __hip_atomic_fetch_add(bar, 1, __ATOMIC_RELAXED, __HIP_MEMORY_SCOPE_AGENT);
        while (__hip_atomic_load(bar, __ATOMIC_RELAXED, __HIP_MEMORY_SCOPE_AGENT) < GRID * gen)
            __builtin_amdgcn_s_sleep(8);
        __builtin_amdgcn_fence(__ATOMIC_ACQUIRE, "agent");
    }
    __syncthreads();
}

union SMem {
    struct { _Float16 A[2 * 16 * RS]; _Float16 Wl[8 * 1024 * 8]; } s;  // 147,968 B
    _Float16 xl[64 * 280];
};

// gx = x @ W_xh + (b_xh + b_hh) for chunk c, grid-strided over gemm blocks.
// Layout: [t 256][sblk 16][wave 8][b_local 4][dim 32][gate 4] f16.
// Epilogue: one contiguous f16x4 store per row (32 lanes = 256B lines).
__device__ void gemm_chunk(const float* __restrict__ x, const f16x8* __restrict__ wxp,
                           const float* __restrict__ b_xh, const float* __restrict__ b_hh,
                           _Float16* __restrict__ gxb, int c, _Float16* xl)
{
    const int tid = threadIdx.x;
    const int t0 = c << 8;
    const int tx = tid & 31;       // dim within block's 32-dim slice
    const int ty = tid >> 5;       // row group 0..15
    for (int T = (int)blockIdx.x - NSER; T < 2048; T += (GRID - NSER)) {
        const int rb = T >> 3, nb = T & 7;
        const int d = nb * 32 + tx;                 // this thread's dim
        for (int it = 0; it < 8; ++it) {
            int idx = it * 512 + tid, row = idx >> 6, kq = idx & 63;
            int rlin = rb * 64 + row, b = rlin >> 8, tl = rlin & 255;
            float4 v = *(const float4*)&x[((size_t)b * TT + t0 + tl) * DD + kq * 4];
            f16x4 h; h[0]=(_Float16)v.x; h[1]=(_Float16)v.y; h[2]=(_Float16)v.z; h[3]=(_Float16)v.w;
            *(f16x4*)&xl[row * 280 + kq * 4] = h;
        }
        __syncthreads();
        float acc[4][4] = {};                       // [row][gate]
#pragma unroll 2
        for (int kk = 0; kk < 32; ++kk) {
            V8 wv[4], xv[4];
#pragma unroll
            for (int g = 0; g < 4; ++g) wv[g].v = wxp[kk * 1024 + g * 256 + d];
#pragma unroll
            for (int r = 0; r < 4; ++r) xv[r].v = *(const f16x8*)&xl[(ty + 16 * r) * 280 + kk * 8];
#pragma unroll
            for (int r = 0; r < 4; ++r)
#pragma unroll
                for (int g = 0; g < 4; ++g)
#pragma unroll
                    for (int q = 0; q < 4; ++q)
                        acc[r][g] = __builtin_amdgcn_fdot2(xv[r].p[q], wv[g].p[q], acc[r][g], false);
        }
        __syncthreads();
        float bb[4];
#pragma unroll
        for (int g = 0; g < 4; ++g) bb[g] = b_xh[g * 256 + d] + b_hh[g * 256 + d];
#pragma unroll
        for (int r = 0; r < 4; ++r) {
            int rlin = rb * 64 + ty + 16 * r, b = rlin >> 8, tl = rlin & 255;
            f16x4 o;
#pragma unroll
            for (int g = 0; g < 4; ++g) o[g] = (_Float16)(acc[r][g] + bb[g]);
            *(f16x4*)&gxb[(((size_t)tl * 16 + (b >> 2)) * 8 + nb) * 512 + (b & 3) * 128 + tx * 4] = o;
        }
    }
}

// ================= serial macros =================
#define FOR_GDH(M) M(0,0) M(0,1) M(1,0) M(1,1) M(2,0) M(2,1) M(3,0) M(3,1)

#define DECLW(g,dh) f16x8 wf_##g##_##dh##_0, wf_##g##_##dh##_1, wf_##g##_##dh##_2, \
                          wf_##g##_##dh##_3, wf_##g##_##dh##_4, wf_##g##_##dh##_5;

#define LOADW1(g,dh,kt) { f16x8 t_; \
    _Pragma("unroll") \
    for (int e = 0; e < 8; ++e) \
        t_[e] = (_Float16)W_hh[(size_t)((kt)*32 + l4*8 + e)*1024 + (g)*256 + wbase + (dh)*16 + l15]; \
    wf_##g##_##dh##_##kt = t_; }

#define LOADW(g,dh) LOADW1(g,dh,0) LOADW1(g,dh,1) LOADW1(g,dh,2) \
                    LOADW1(g,dh,3) LOADW1(g,dh,4) LOADW1(g,dh,5)

#define KTR(kt,dh) { f16x8 af_ = *(const f16x8*)&Ab[(kt)*32 + l4*8]; \
    ac0_ = __builtin_amdgcn_mfma_f32_16x16x32_f16(af_, wf_0_##dh##_##kt, ac0_, 0,0,0); \
    ac1_ = __builtin_amdgcn_mfma_f32_16x16x32_f16(af_, wf_1_##dh##_##kt, ac1_, 0,0,0); \
    ac2_ = __builtin_amdgcn_mfma_f32_16x16x32_f16(af_, wf_2_##dh##_##kt, ac2_, 0,0,0); \
    ac3_ = __builtin_amdgcn_mfma_f32_16x16x32_f16(af_, wf_3_##dh##_##kt, ac3_, 0,0,0); }

#define BLD(g,dh,kt) (*(const f16x8*)&Wl[(size_t)((((kt)-6)*4 + l4)*1024 + (g)*256 + wbase + (dh)*16 + l15)*8])

#define KTL(kt,dh) { f16x8 af_ = *(const f16x8*)&Ab[(kt)*32 + l4*8]; \
    ac0_ = __builtin_amdgcn_mfma_f32_16x16x32_f16(af_, BLD(0,dh,kt), ac0_, 0,0,0); \
    ac1_ = __builtin_amdgcn_mfma_f32_16x16x32_f16(af_, BLD(1,dh,kt), ac1_, 0,0,0); \
    ac2_ = __builtin_amdgcn_mfma_f32_16x16x32_f16(af_, BLD(2,dh,kt), ac2_, 0,0,0); \
    ac3_ = __builtin_amdgcn_mfma_f32_16x16x32_f16(af_, BLD(3,dh,kt), ac3_, 0,0,0); }

// One batch per lane-group: batch = blk*4 + l4, rows 4*l4 (h0), 4*l4+1 (h1).
// Layer0 gates = ac[0] + gx; layer1 gates = ac[0] + ac[1] + 2*b_hh.
#define UPD(dh) { \
    const int gb_ = blk*PB + l4; \
    const int d_  = wbase + (dh)*16 + l15; \
    float h0n_ = 0.f, h1n_ = 0.f; \
    if (l0act) { \
        float gi_ = ac0_[0] + (float)gv_##dh[0]; \
        float gf_ = ac1_[0] + (float)gv_##dh[1]; \
        float gg_ = ac2_[0] + (float)gv_##dh[2]; \
        float go_ = ac3_[0] + (float)gv_##dh[3]; \
        c0s_##dh = c0s_##dh*sigm(gf_) + sigm(gi_)*tanh_f(gg_); \
        h0n_ = sigm(go_)*tanh_f(c0s_##dh); \
    } \
    if (l1act) { \
        float gi_ = ac0_[0] + ac0_[1] + bh2_##dh##_0; \
        float gf_ = ac1_[0] + ac1_[1] + bh2_##dh##_1; \
        float gg_ = ac2_[0] + ac2_[1] + bh2_##dh##_2; \
        float go_ = ac3_[0] + ac3_[1] + bh2_##dh##_3; \
        c1s_##dh = c1s_##dh*sigm(gf_) + sigm(gi_)*tanh_f(gg_); \
        h1n_ = sigm(go_)*tanh_f(c1s_##dh); \
        out[((size_t)gb_*TT + (t0 + p - 1))*HH + d_] = h1n_; \
    } \
    A[(parx*16 + 4*l4 + 0)*RS + d_] = (_Float16)h0n_; \
    A[(parx*16 + 4*l4 + 1)*RS + d_] = (_Float16)h1n_; \
    if (lastc) { \
        if (l0act && p == CHUNK-1) { out[FIN + gb_*256 + d_] = h0n_; out[FIN + 32768 + gb_*256 + d_] = c0s_##dh; } \
        if (p == nph-1) { out[FIN + 16384 + gb_*256 + d_] = h1n_; out[FIN + 49152 + gb_*256 + d_] = c1s_##dh; } \
    } }

#define HALF(dh) { \
    f16x4 gv_##dh = {}; \
    if (l0act) \
        gv_##dh = *(const f16x4*)&gxc[(((size_t)p * 16 + blk) * 8 + w) * 512 + l4*128 + (dh)*64 + l15*4]; \
    f32x4 ac0_ = {}, ac1_ = {}, ac2_ = {}, ac3_ = {}; \
    KTR(0,dh) KTR(1,dh) KTR(2,dh) KTR(3,dh) KTR(4,dh) KTR(5,dh) \
    KTL(6,dh) KTL(7,dh) \
    UPD(dh) }

// Persistent fused kernel: blocks 0..15 = serial recurrence, rest = gx GEMM.
__global__ __launch_bounds__(512, 2) void lstm_coop(
    const float* __restrict__ x,
    const _Float16* __restrict__ wxp16,
    const float* __restrict__ b_xh, const float* __restrict__ b_hh,
    const float* __restrict__ W_hh,
    float* __restrict__ out,
    _Float16* __restrict__ gx0, _Float16* __restrict__ gx1,
    int* __restrict__ bar, int overlap)
{
    __shared__ SMem sm;
    const int tid = threadIdx.x;
    const f16x8* wxp = (const f16x8*)wxp16;

    if (blockIdx.x < NSER) {
        // ================= serial path =================
        _Float16* A  = sm.s.A;
        _Float16* Wl = sm.s.Wl;
        const int blk = blockIdx.x;
        const int l   = tid & 63;
        const int l15 = l & 15;
        const int l4  = l >> 4;
        const int w   = tid >> 6;
        const int wbase = w * 32;

        // LDS weights: k in [192,256)
        for (int v = tid; v < 8192; v += 512) {
            int cr = v >> 10, col = v & 1023;
            f16x8 t;
#pragma unroll
            for (int e = 0; e < 8; ++e)
                t[e] = (_Float16)W_hh[(size_t)(192 + cr * 8 + e) * 1024 + col];
            *(f16x8*)&Wl[(size_t)v * 8] = t;
        }
        // register weights: k in [0,192), 48 named f16x8
        FOR_GDH(DECLW)
        FOR_GDH(LOADW)

        float bh2_0_0 = 2.f*b_hh[0*256 + wbase + l15],      bh2_0_1 = 2.f*b_hh[1*256 + wbase + l15];
        float bh2_0_2 = 2.f*b_hh[2*256 + wbase + l15],      bh2_0_3 = 2.f*b_hh[3*256 + wbase + l15];
        float bh2_1_0 = 2.f*b_hh[0*256 + wbase + 16 + l15], bh2_1_1 = 2.f*b_hh[1*256 + wbase + 16 + l15];
        float bh2_1_2 = 2.f*b_hh[2*256 + wbase + 16 + l15], bh2_1_3 = 2.f*b_hh[3*256 + wbase + 16 + l15];

        float c0s_0 = 0.f, c0s_1 = 0.f, c1s_0 = 0.f, c1s_1 = 0.f;
        for (int i = tid; i < 16 * RS; i += 512) A[i] = (_Float16)0;   // parity-0 A = 0

        int gen = 0;
        gridbar(bar, ++gen);                 // wait for chunk-0 gx

        const size_t FIN = (size_t)BB * TT * HH;
        for (int c = 0; c < NCHUNK; ++c) {
            const _Float16* gxc = (c & 1) ? gx1 : gx0;
            const int t0 = c << 8;
            const int nph = (c == NCHUNK - 1) ? CHUNK + 1 : CHUNK;
            const bool lastc = (c == NCHUNK - 1);
            for (int p = 0; p < nph; ++p) {
                const int par = p & 1, parx = par ^ 1;
                const bool l0act = (p < CHUNK);
                const bool l1act = (c > 0) || (p > 0);
                const _Float16* Ab = A + (par * 16 + l15) * RS;
                HALF(0)
                HALF(1)
                if (p + 1 < nph) {
                    // raw barrier: only LDS (A) writes must be visible cross-wave.
                    asm volatile("s_waitcnt lgkmcnt(0)" ::: "memory");
                    __builtin_amdgcn_s_barrier();
                }
            }
            if (c < NCHUNK - 1) {
                gridbar(bar, ++gen);
                if (!overlap) gridbar(bar, ++gen);
            }
        }
    } else {
        // ================= gemm path =================
        gemm_chunk(x, wxp, b_xh, b_hh, gx0, 0, sm.xl);
        int gen = 0;
        gridbar(bar, ++gen);
        for (int c = 0; c < NCHUNK - 1; ++c) {
            if (overlap) {
                gemm_chunk(x, wxp, b_xh, b_hh, ((c + 1) & 1) ? gx1 : gx0, c + 1, sm.xl);
                gridbar(bar, ++gen);
            } else {
                gridbar(bar, ++gen);
                gemm_chunk(x, wxp, b_xh, b_hh, gx0, c + 1, sm.xl);
                gridbar(bar, ++gen);
            }
        }
    }
}

extern "C" void kernel_launch(void* const* d_in, const int* in_sizes, int n_in,
                              void* d_out, int out_size, void* d_ws, size_t ws_size,
                              hipStream_t stream) {
    const float* x    = (const float*)d_in[0];
    const float* W_xh = (const float*)d_in[1];
    const float* b_xh = (const float*)d_in[2];
    const float* W_hh = (const float*)d_in[3];
    const float* b_hh = (const float*)d_in[4];
    float* out = (float*)d_out;

    char* ws = (char*)d_ws;
    _Float16* wxp = (_Float16*)ws;                          // 512 KB packed W_xh
    int* bar      = (int*)(ws + (512 << 10));               // barrier counter
    char* gxbase  = ws + (512 << 10) + 256;
    const size_t gxb = (size_t)64 * 256 * 1024 * 2;         // 33.55 MB per gx buffer
    _Float16* gx0 = (_Float16*)gxbase;
    int overlap = (ws_size >= (size_t)(512 << 10) + 256 + 2 * gxb) ? 1 : 0;
    _Float16* gx1 = overlap ? (_Float16*)(gxbase + gxb) : gx0;

    pack_w<<<1024, 256, 0, stream>>>(W_xh, wxp);
    hipMemsetAsync(bar, 0, 4, stream);
    lstm_coop<<<GRID, 512, 0, stream>>>(x, wxp, b_xh, b_hh, W_hh, out, gx0, gx1, bar, overlap);
}